// Round 1
// baseline (96.595 us; speedup 1.0000x reference)
//
#include <hip/hip_runtime.h>
#include <hip/hip_bf16.h>

// Problem constants (from reference)
#define BATCH      8
#define S_BYTES    8192
#define NUM_EMB    384
#define BYTE_DIM   128
#define EMB_DIM    1024
#define NUM_TOKENS 2048
#define SCALE_F    11.313708498984761f   // sqrt(128)

#define M_TOTAL (BATCH * NUM_TOKENS)     // 16384 output token rows
#define SEG_STRIDE 2064                  // 2049 entries padded

typedef __bf16 bf16x8 __attribute__((ext_vector_type(8)));
typedef float  floatx4 __attribute__((ext_vector_type(4)));

// ---------------------------------------------------------------------------
// Kernel A (fused):
//   blockIdx < 256  -> segment-boundary precompute (seg[b][t] = lower_bound)
//   blockIdx >= 256 -> proj = emb @ W^T  as a 24-block 128x128 bf16 MFMA GEMM
//                      (M=384 emb rows, N=1024 w rows, K=128). proj is fp32,
//                      1.5 MB -> stays L2-resident for kernel B's gathers.
// Linearity: mean(emb[x]*SCALE) @ W^T == SCALE/cnt * sum(proj[x]), so the
// 16384-row GEMM of the previous version is replaced by this 384-row one.
// ---------------------------------------------------------------------------
__global__ __launch_bounds__(256) void prep_kernel(
    const int*   __restrict__ bg,        // [B, S_BYTES] sorted per row
    int*         __restrict__ seg,       // [B, SEG_STRIDE]
    const float* __restrict__ emb,       // [NUM_EMB, BYTE_DIM] fp32
    const float* __restrict__ w,         // [EMB_DIM, BYTE_DIM] fp32
    float*       __restrict__ proj)      // [NUM_EMB, EMB_DIM] fp32 out
{
    __shared__ __hip_bfloat16 sA[128 * 128];   // 32 KB  emb tile [m][k]
    __shared__ __hip_bfloat16 sB[128 * 128];   // 32 KB  w   tile [n][k]

    if (blockIdx.x < 256) {
        // --- segment boundaries (unchanged, known-good) ---
        const int gid = blockIdx.x * 256 + threadIdx.x;   // 0..65535
        const int b = gid >> 13;
        const int i = gid & (S_BYTES - 1);
        const int g  = bg[gid];
        const int gp = (i == 0) ? -1 : bg[gid - 1];
        int* __restrict__ srow = seg + b * SEG_STRIDE;
        for (int t = gp + 1; t <= g; ++t) srow[t] = i;
        if (i == S_BYTES - 1) {
            for (int t = g + 1; t <= NUM_TOKENS; ++t) srow[t] = S_BYTES;
        }
        return;
    }

    // --- tiny GEMM: proj[m][n] = sum_k emb[m][k] * w[n][k] ---
    const int gb = blockIdx.x - 256;     // 0..23
    const int mb = gb >> 3;              // 0..2  (384 = 3 * 128)
    const int nb = gb & 7;               // 0..7  (1024 = 8 * 128)
    const int m0 = mb * 128;
    const int n0 = nb * 128;
    const int tid = threadIdx.x;

    {   // stage fp32 -> bf16 into LDS (coalesced float4 reads, 8B LDS writes)
        const float4* __restrict__ gA = (const float4*)(emb + (size_t)m0 * BYTE_DIM);
        const float4* __restrict__ gB = (const float4*)(w   + (size_t)n0 * BYTE_DIM);
        #pragma unroll
        for (int i = 0; i < 16; ++i) {
            const int idx = tid + i * 256;            // float4 index 0..4095
            const float4 a = gA[idx];
            const float4 c = gB[idx];
            alignas(8) __hip_bfloat16 ha[4] = {
                __float2bfloat16(a.x), __float2bfloat16(a.y),
                __float2bfloat16(a.z), __float2bfloat16(a.w)};
            alignas(8) __hip_bfloat16 hb[4] = {
                __float2bfloat16(c.x), __float2bfloat16(c.y),
                __float2bfloat16(c.z), __float2bfloat16(c.w)};
            *(uint2*)(sA + idx * 4) = *(const uint2*)ha;
            *(uint2*)(sB + idx * 4) = *(const uint2*)hb;
        }
    }
    __syncthreads();

    const int wave = tid >> 6;
    const int lane = tid & 63;
    const int wm = wave >> 1;        // 0..1
    const int wn = wave & 1;         // 0..1
    const int r    = lane & 15;
    const int quad = lane >> 4;

    floatx4 acc[4][4] = {};

    #pragma unroll
    for (int kk = 0; kk < 4; ++kk) {
        bf16x8 af[4], bfr[4];
        #pragma unroll
        for (int i = 0; i < 4; ++i)
            af[i] = *(const bf16x8*)(sA + (wm * 64 + i * 16 + r) * BYTE_DIM + kk * 32 + quad * 8);
        #pragma unroll
        for (int j = 0; j < 4; ++j)
            bfr[j] = *(const bf16x8*)(sB + (wn * 64 + j * 16 + r) * BYTE_DIM + kk * 32 + quad * 8);
        #pragma unroll
        for (int i = 0; i < 4; ++i)
            #pragma unroll
            for (int j = 0; j < 4; ++j)
                acc[i][j] = __builtin_amdgcn_mfma_f32_16x16x32_bf16(af[i], bfr[j], acc[i][j], 0, 0, 0);
    }

    // plain (cached) stores: kernel B wants proj resident in L2
    #pragma unroll
    for (int i = 0; i < 4; ++i) {
        const int mrow = m0 + wm * 64 + i * 16 + quad * 4;
        #pragma unroll
        for (int j = 0; j < 4; ++j) {
            const int ncol = n0 + wn * 64 + j * 16 + r;
            float* __restrict__ p = proj + (size_t)mrow * EMB_DIM + ncol;
            #pragma unroll
            for (int reg = 0; reg < 4; ++reg)
                p[(size_t)reg * EMB_DIM] = acc[i][j][reg];
        }
    }
}

// ---------------------------------------------------------------------------
// Kernel B: pooled projection. One 256-thread block per output token row.
// out[m][:] = SCALE/cnt * sum_{i in seg} proj[x[i]][:]   (all fp32)
// Loop bounds and x[i] are block-uniform -> scalar loads; gather is a fully
// coalesced 4 KB row read per byte (proj is L2-resident). Output written
// nontemporally (64 MB streaming, don't evict proj).
// ---------------------------------------------------------------------------
__global__ __launch_bounds__(256) void pool_kernel(
    const int*   __restrict__ x,         // [B, S_BYTES]
    const int*   __restrict__ seg,       // [B, SEG_STRIDE]
    const float* __restrict__ proj,      // [NUM_EMB, EMB_DIM] fp32
    float*       __restrict__ out)       // [M_TOTAL, EMB_DIM] fp32
{
    const int m = blockIdx.x;            // 0..16383
    const int b = m >> 11;
    const int t = m & (NUM_TOKENS - 1);

    const int s   = seg[b * SEG_STRIDE + t];
    const int e   = seg[b * SEG_STRIDE + t + 1];
    const int cnt = e - s;

    const int* __restrict__ xrow = x + b * S_BYTES;
    const floatx4* __restrict__ pv = (const floatx4*)proj;  // [NUM_EMB][256]

    floatx4 acc = {0.f, 0.f, 0.f, 0.f};
    #pragma unroll 4
    for (int i = s; i < e; ++i) {
        const int ei = xrow[i];                 // uniform -> scalar load
        acc += pv[ei * 256 + threadIdx.x];      // 16 B/lane, 4 KB/row coalesced
    }

    const float inv = SCALE_F / (float)(cnt > 1 ? cnt : 1);
    acc *= inv;

    __builtin_nontemporal_store(acc, (floatx4*)(out + (size_t)m * EMB_DIM) + threadIdx.x);
}

extern "C" void kernel_launch(void* const* d_in, const int* in_sizes, int n_in,
                              void* d_out, int out_size, void* d_ws, size_t ws_size,
                              hipStream_t stream) {
    const int*   x   = (const int*)d_in[0];     // [8, 8192] int32
    const int*   bg  = (const int*)d_in[1];     // [8, 8192] int32 (sorted rows)
    const float* emb = (const float*)d_in[2];   // [384, 128] fp32
    const float* w   = (const float*)d_in[3];   // [1024, 128] fp32
    float*       out = (float*)d_out;           // [16384, 1024] fp32

    // ws layout: proj fp32 [384,1024] (1.5 MB) | seg int [8][2064]
    float* proj = (float*)d_ws;
    int*   seg  = (int*)((char*)d_ws + (size_t)NUM_EMB * EMB_DIM * sizeof(float));

    prep_kernel<<<256 + 24, 256, 0, stream>>>(bg, seg, emb, w, proj);
    pool_kernel<<<M_TOTAL, 256, 0, stream>>>(x, seg, proj, out);
}